// Round 4
// baseline (662.183 us; speedup 1.0000x reference)
//
#include <hip/hip_runtime.h>

#define Bsz  2048
#define Tlen 512
#define Din  32
#define Hd   64
#define BT   16            // real batches per block (M=16 MFMA tile, no ghost rows)
#define HS   72            // h-tile row stride in f16 elems (144B, 16B-aligned reads)
#define BUFE 2048          // f16 elems per h buffer (4096 B) -> XOR-toggle double buffer

typedef _Float16 half8 __attribute__((ext_vector_type(8)));
typedef float    f32x4 __attribute__((ext_vector_type(4)));

// weights pre-scaled by -log2(e) (r,z) and -2*log2(e) (n):
//   sigmoid(raw) = rcp(1 + exp2(g_scaled));  tanh(raw) = 2*rcp(1+exp2(y_scaled)) - 1
#define MFMA(a, b, c) __builtin_amdgcn_mfma_f32_16x16x32_f16((a), (b), (c), 0, 0, 0)

__device__ __forceinline__ half8 load8s(const float* p, float s) {
    half8 r;
#pragma unroll
    for (int j = 0; j < 8; ++j) r[j] = (_Float16)(p[j] * s);
    return r;
}
__device__ __forceinline__ half8 cvt8(float4 a, float4 b) {
    half8 r;
    r[0] = (_Float16)a.x; r[1] = (_Float16)a.y; r[2] = (_Float16)a.z; r[3] = (_Float16)a.w;
    r[4] = (_Float16)b.x; r[5] = (_Float16)b.y; r[6] = (_Float16)b.z; r[7] = (_Float16)b.w;
    return r;
}

// gates + state update + (optional) LDS writeback for 4 C-rows (all real)
__device__ __forceinline__ void gate_update(const f32x4& gr, const f32x4& gz,
                                            const f32x4& anx, const f32x4& anh,
                                            float hst[4], _Float16* dst, bool wr) {
#pragma unroll
    for (int r = 0; r < 4; ++r) {
        float rr = __builtin_amdgcn_rcpf(1.0f + __builtin_amdgcn_exp2f(gr[r]));
        float zz = __builtin_amdgcn_rcpf(1.0f + __builtin_amdgcn_exp2f(gz[r]));
        float yy = anx[r] + rr * anh[r];
        float tt = __builtin_amdgcn_rcpf(1.0f + __builtin_amdgcn_exp2f(yy));
        float nn = 2.0f * tt - 1.0f;
        hst[r] = nn + zz * (hst[r] - nn);
        if (wr) dst[r * HS] = (_Float16)hst[r];
    }
}

__global__ __launch_bounds__(512, 2)
void gru_fused(const float* __restrict__ x,
               const float* __restrict__ Wih0, const float* __restrict__ Whh0,
               const float* __restrict__ bih0, const float* __restrict__ bhh0,
               const float* __restrict__ Wih1, const float* __restrict__ Whh1,
               const float* __restrict__ bih1, const float* __restrict__ bhh1,
               const float* __restrict__ fcw,  const float* __restrict__ fcb,
               float* __restrict__ out)
{
    // arena: h1 buffers at [0],[BUFE]; h2 buffers at [2*BUFE],[3*BUFE]
    __shared__ _Float16 arena[4 * BUFE];
    __shared__ float hfin[BT][Hd];

    const int tid  = threadIdx.x;
    const int lane = tid & 63;
    const int wave = tid >> 6;
    const int grp  = wave >> 2;            // 0 = layer1 waves, 1 = layer2 waves
    const int wg   = wave & 3;             // which 16 gate-cols this wave owns
    const int m    = lane & 15;            // A-frag row = batch (ALL REAL)
    const int quad = lane >> 4;            // k-chunk (A/B), row-group (C/D)
    const int col  = (wg << 4) + m;        // gate/h column 0..63
    const int b0   = blockIdx.x << 4;      // 16 batches per block

    for (int idx = tid; idx < 4 * BUFE; idx += 512) arena[idx] = (_Float16)0.f;

    const float sRZ = -1.44269504f;        // -log2(e)
    const float sN  = -2.88539008f;        // -2*log2(e)

    // ---- persistent pre-scaled weight B-fragments (B[k][n] = W[n][k]) ----
    half8 wx[2][3], wh[2][3];
    float brz0, brz1, bin_, bhn_;

    if (grp == 0) {
        wx[0][0] = load8s(Wih0 + (      col) * Din + quad * 8, sRZ);
        wx[0][1] = load8s(Wih0 + ( 64 + col) * Din + quad * 8, sRZ);
        wx[0][2] = load8s(Wih0 + (128 + col) * Din + quad * 8, sN);
#pragma unroll
        for (int kb = 0; kb < 2; ++kb) {
            wh[kb][0] = load8s(Whh0 + (      col) * Hd + kb * 32 + quad * 8, sRZ);
            wh[kb][1] = load8s(Whh0 + ( 64 + col) * Hd + kb * 32 + quad * 8, sRZ);
            wh[kb][2] = load8s(Whh0 + (128 + col) * Hd + kb * 32 + quad * 8, sN);
        }
        brz0 = sRZ * (bih0[col] + bhh0[col]);
        brz1 = sRZ * (bih0[64 + col] + bhh0[64 + col]);
        bin_ = sN * bih0[128 + col];
        bhn_ = sN * bhh0[128 + col];
    } else {
#pragma unroll
        for (int kb = 0; kb < 2; ++kb) {
            wx[kb][0] = load8s(Wih1 + (      col) * Hd + kb * 32 + quad * 8, sRZ);
            wx[kb][1] = load8s(Wih1 + ( 64 + col) * Hd + kb * 32 + quad * 8, sRZ);
            wx[kb][2] = load8s(Wih1 + (128 + col) * Hd + kb * 32 + quad * 8, sN);
            wh[kb][0] = load8s(Whh1 + (      col) * Hd + kb * 32 + quad * 8, sRZ);
            wh[kb][1] = load8s(Whh1 + ( 64 + col) * Hd + kb * 32 + quad * 8, sRZ);
            wh[kb][2] = load8s(Whh1 + (128 + col) * Hd + kb * 32 + quad * 8, sN);
        }
        brz0 = sRZ * (bih1[col] + bhh1[col]);
        brz1 = sRZ * (bih1[64 + col] + bhh1[64 + col]);
        bin_ = sN * bih1[128 + col];
        bhn_ = sN * bhh1[128 + col];
    }

    // x prefetch (L1 waves); all 16 m-rows are real batches now
    const float* xp = x + (size_t)(b0 + m) * Tlen * Din + quad * 8;
    float4 xa, xb;
    if (grp == 0) { xa = *(const float4*)xp; xb = *(const float4*)(xp + 4); }

    const int rdoff = m * HS + quad * 8;          // lane part of A-read address
    const int wroff = (quad * 4) * HS + col;      // lane part of C-write address
    float hst[4] = {0.f, 0.f, 0.f, 0.f};
    __syncthreads();

    int ro = BUFE;                                // peel-0 reads zeros from buf1

    // ---------- peel i = 0 : L1 only; h1[-1]=0 so h-side MFMAs are skipped ----------
    if (grp == 0) {
        const float* xn = xp + Din;               // prefetch x[1]
        float4 pa = *(const float4*)xn, pb = *(const float4*)(xn + 4);
        half8 ax = cvt8(xa, xb);
        f32x4 gr  = {brz0, brz0, brz0, brz0};
        f32x4 gz  = {brz1, brz1, brz1, brz1};
        f32x4 anx = {bin_, bin_, bin_, bin_};
        f32x4 anh = {bhn_, bhn_, bhn_, bhn_};
        gr  = MFMA(ax, wx[0][0], gr);
        gz  = MFMA(ax, wx[0][1], gz);
        anx = MFMA(ax, wx[0][2], anx);
        gate_update(gr, gz, anx, anh, hst, arena + ((ro ^ BUFE) + wroff), true);
        xa = pa; xb = pb; xp = xn;
    }
    __syncthreads();
    ro ^= BUFE;                                   // -> 0

    // ---------- main: i = 1..511, both groups active, no predicates ----------
    for (int i = 1; i < Tlen; ++i) {
        const int wo = ro ^ BUFE;
        if (grp == 0) {
            const float* xn = xp + ((i + 1 < Tlen) ? Din : 0);
            float4 pa = *(const float4*)xn, pb = *(const float4*)(xn + 4);
            half8 ax = cvt8(xa, xb);
            const _Float16* s1 = arena + (ro + rdoff);
            half8 ah0 = *(const half8*)s1;
            half8 ah1 = *(const half8*)(s1 + 32);
            f32x4 arx = {brz0, brz0, brz0, brz0};
            f32x4 azx = {brz1, brz1, brz1, brz1};
            f32x4 anx = {bin_, bin_, bin_, bin_};
            f32x4 arh = {0.f, 0.f, 0.f, 0.f};
            f32x4 azh = {0.f, 0.f, 0.f, 0.f};
            f32x4 anh = {bhn_, bhn_, bhn_, bhn_};
            // h-side first (critical path from ds_read); depth-2 chains
            arh = MFMA(ah0, wh[0][0], arh); arh = MFMA(ah1, wh[1][0], arh);
            azh = MFMA(ah0, wh[0][1], azh); azh = MFMA(ah1, wh[1][1], azh);
            anh = MFMA(ah0, wh[0][2], anh); anh = MFMA(ah1, wh[1][2], anh);
            arx = MFMA(ax, wx[0][0], arx);
            azx = MFMA(ax, wx[0][1], azx);
            anx = MFMA(ax, wx[0][2], anx);
            f32x4 gr = arx + arh, gz = azx + azh;
            gate_update(gr, gz, anx, anh, hst, arena + (wo + wroff), true);
            xa = pa; xb = pb; xp = xn;
        } else {
            const _Float16* s1 = arena + (ro + rdoff);            // h1[i-1]
            const _Float16* s2 = s1 + 2 * BUFE;                   // h2[i-2]
            half8 ax0 = *(const half8*)s1;
            half8 ax1 = *(const half8*)(s1 + 32);
            half8 ah0 = *(const half8*)s2;
            half8 ah1 = *(const half8*)(s2 + 32);
            f32x4 arx = {brz0, brz0, brz0, brz0};
            f32x4 azx = {brz1, brz1, brz1, brz1};
            f32x4 anx = {bin_, bin_, bin_, bin_};
            f32x4 arh = {0.f, 0.f, 0.f, 0.f};
            f32x4 azh = {0.f, 0.f, 0.f, 0.f};
            f32x4 anh = {bhn_, bhn_, bhn_, bhn_};
            arx = MFMA(ax0, wx[0][0], arx); arx = MFMA(ax1, wx[1][0], arx);
            azx = MFMA(ax0, wx[0][1], azx); azx = MFMA(ax1, wx[1][1], azx);
            anx = MFMA(ax0, wx[0][2], anx); anx = MFMA(ax1, wx[1][2], anx);
            arh = MFMA(ah0, wh[0][0], arh); arh = MFMA(ah1, wh[1][0], arh);
            azh = MFMA(ah0, wh[0][1], azh); azh = MFMA(ah1, wh[1][1], azh);
            anh = MFMA(ah0, wh[0][2], anh); anh = MFMA(ah1, wh[1][2], anh);
            f32x4 gr = arx + arh, gz = azx + azh;
            gate_update(gr, gz, anx, anh, hst, arena + (2 * BUFE + wo + wroff), true);
        }
        __syncthreads();
        ro = wo;
    }

    // ---------- peel i = T : L2 only, computes h2[T-1], no LDS writeback ----------
    if (grp == 1) {
        const _Float16* s1 = arena + (ro + rdoff);
        const _Float16* s2 = s1 + 2 * BUFE;
        half8 ax0 = *(const half8*)s1;
        half8 ax1 = *(const half8*)(s1 + 32);
        half8 ah0 = *(const half8*)s2;
        half8 ah1 = *(const half8*)(s2 + 32);
        f32x4 arx = {brz0, brz0, brz0, brz0};
        f32x4 azx = {brz1, brz1, brz1, brz1};
        f32x4 anx = {bin_, bin_, bin_, bin_};
        f32x4 arh = {0.f, 0.f, 0.f, 0.f};
        f32x4 azh = {0.f, 0.f, 0.f, 0.f};
        f32x4 anh = {bhn_, bhn_, bhn_, bhn_};
        arx = MFMA(ax0, wx[0][0], arx); arx = MFMA(ax1, wx[1][0], arx);
        azx = MFMA(ax0, wx[0][1], azx); azx = MFMA(ax1, wx[1][1], azx);
        anx = MFMA(ax0, wx[0][2], anx); anx = MFMA(ax1, wx[1][2], anx);
        arh = MFMA(ah0, wh[0][0], arh); arh = MFMA(ah1, wh[1][0], arh);
        azh = MFMA(ah0, wh[0][1], azh); azh = MFMA(ah1, wh[1][1], azh);
        anh = MFMA(ah0, wh[0][2], anh); anh = MFMA(ah1, wh[1][2], anh);
        f32x4 gr = arx + arh, gz = azx + azh;
        gate_update(gr, gz, anx, anh, hst, nullptr, false);
        // C rows quad*4+r are all real batches now
#pragma unroll
        for (int r = 0; r < 4; ++r) hfin[quad * 4 + r][col] = hst[r];
    }
    __syncthreads();
    if (tid < BT) {                                // FC head
        float acc = fcb[0];
        for (int c = 0; c < Hd; ++c) acc += hfin[tid][c] * fcw[c];
        out[b0 + tid] = acc;
    }
}

extern "C" void kernel_launch(void* const* d_in, const int* in_sizes, int n_in,
                              void* d_out, int out_size, void* d_ws, size_t ws_size,
                              hipStream_t stream) {
    gru_fused<<<dim3(Bsz / BT), dim3(512), 0, stream>>>(
        (const float*)d_in[0],
        (const float*)d_in[1], (const float*)d_in[2],
        (const float*)d_in[3], (const float*)d_in[4],
        (const float*)d_in[5], (const float*)d_in[6],
        (const float*)d_in[7], (const float*)d_in[8],
        (const float*)d_in[9], (const float*)d_in[10],
        (float*)d_out);
}

// Round 5
// 551.777 us; speedup vs baseline: 1.2001x; 1.2001x over previous
//
#include <hip/hip_runtime.h>

#define Bsz  2048
#define Tlen 512
#define Din  32
#define Hd   64
#define BT   16            // real batches per block (M=16 MFMA tile, no ghost rows)
#define HS   72            // h-tile row stride in f16 elems (144B, 16B-aligned reads)
#define BUFE 2048          // f16 elems per h buffer (4096 B) -> XOR-toggle double buffer
#define CHUNK 16           // x timesteps staged per global_load_lds burst
#define XSTR  2064         // LDS bytes per batch per chunk (2048 + 16 pad, 16B-aligned)
#define XBUFB (BT * XSTR)  // bytes per x chunk buffer (33024)

typedef _Float16 half8 __attribute__((ext_vector_type(8)));
typedef float    f32x4 __attribute__((ext_vector_type(4)));

// weights pre-scaled by -log2(e) (r,z) and -2*log2(e) (n):
//   sigmoid(raw) = rcp(1 + exp2(g_scaled));  tanh(raw) = 2*rcp(1+exp2(y_scaled)) - 1
#define MFMA(a, b, c) __builtin_amdgcn_mfma_f32_16x16x32_f16((a), (b), (c), 0, 0, 0)

__device__ __forceinline__ half8 load8s(const float* p, float s) {
    half8 r;
#pragma unroll
    for (int j = 0; j < 8; ++j) r[j] = (_Float16)(p[j] * s);
    return r;
}
__device__ __forceinline__ half8 cvt8(float4 a, float4 b) {
    half8 r;
    r[0] = (_Float16)a.x; r[1] = (_Float16)a.y; r[2] = (_Float16)a.z; r[3] = (_Float16)a.w;
    r[4] = (_Float16)b.x; r[5] = (_Float16)b.y; r[6] = (_Float16)b.z; r[7] = (_Float16)b.w;
    return r;
}

// gates + state update + (optional) LDS writeback for 4 C-rows (all real)
__device__ __forceinline__ void gate_update(const f32x4& gr, const f32x4& gz,
                                            const f32x4& anx, const f32x4& anh,
                                            float hst[4], _Float16* dst, bool wr) {
#pragma unroll
    for (int r = 0; r < 4; ++r) {
        float rr = __builtin_amdgcn_rcpf(1.0f + __builtin_amdgcn_exp2f(gr[r]));
        float zz = __builtin_amdgcn_rcpf(1.0f + __builtin_amdgcn_exp2f(gz[r]));
        float yy = anx[r] + rr * anh[r];
        float tt = __builtin_amdgcn_rcpf(1.0f + __builtin_amdgcn_exp2f(yy));
        float nn = 2.0f * tt - 1.0f;
        hst[r] = nn + zz * (hst[r] - nn);
        if (wr) dst[r * HS] = (_Float16)hst[r];
    }
}

// stage one 16-step x chunk (32 KB) into LDS buffer p via async global->LDS DMA.
// issue g = wave*4+j covers batch b = g>>1, kilobyte-half hh = g&1: 64 lanes x 16B,
// LDS dest contiguous per issue (wave-uniform base + lane*16) as HW requires.
__device__ __forceinline__ void stage_chunk(const float* __restrict__ x, char* xs,
                                            int wave, int lane, int b0, int t0, int p) {
#pragma unroll
    for (int j = 0; j < 4; ++j) {
        const int g  = wave * 4 + j;
        const int b  = g >> 1;
        const int hh = g & 1;
        const float* gp = x + (size_t)(b0 + b) * (Tlen * Din) + (size_t)t0 * Din
                            + hh * 256 + lane * 4;
        char* lp = xs + p * XBUFB + b * XSTR + hh * 1024 + lane * 16;
        __builtin_amdgcn_global_load_lds(
            (const __attribute__((address_space(1))) void*)gp,
            (__attribute__((address_space(3))) void*)lp, 16, 0, 0);
    }
}

__global__ __launch_bounds__(512, 2)
void gru_fused(const float* __restrict__ x,
               const float* __restrict__ Wih0, const float* __restrict__ Whh0,
               const float* __restrict__ bih0, const float* __restrict__ bhh0,
               const float* __restrict__ Wih1, const float* __restrict__ Whh1,
               const float* __restrict__ bih1, const float* __restrict__ bhh1,
               const float* __restrict__ fcw,  const float* __restrict__ fcb,
               float* __restrict__ out)
{
    // arena: h1 buffers at [0],[BUFE]; h2 buffers at [2*BUFE],[3*BUFE]
    __shared__ _Float16 arena[4 * BUFE];
    __shared__ __attribute__((aligned(16))) char xstage[2 * XBUFB];
    __shared__ float hfin[BT][Hd];

    const int tid  = threadIdx.x;
    const int lane = tid & 63;
    const int wave = tid >> 6;
    const int grp  = wave >> 2;            // 0 = layer1 waves, 1 = layer2 waves
    const int wg   = wave & 3;             // which 16 gate-cols this wave owns
    const int m    = lane & 15;            // A-frag row = batch (ALL REAL)
    const int quad = lane >> 4;            // k-chunk (A/B), row-group (C/D)
    const int col  = (wg << 4) + m;        // gate/h column 0..63
    const int b0   = blockIdx.x << 4;      // 16 batches per block

    for (int idx = tid; idx < 4 * BUFE; idx += 512) arena[idx] = (_Float16)0.f;

    // pre-stage chunks 0 (steps 0..15 -> buf0) and 1 (steps 16..31 -> buf1)
    stage_chunk(x, xstage, wave, lane, b0, 0, 0);
    stage_chunk(x, xstage, wave, lane, b0, CHUNK, 1);

    const float sRZ = -1.44269504f;        // -log2(e)
    const float sN  = -2.88539008f;        // -2*log2(e)

    // ---- persistent pre-scaled weight B-fragments (B[k][n] = W[n][k]) ----
    half8 wx[2][3], wh[2][3];
    float brz0, brz1, bin_, bhn_;

    if (grp == 0) {
        wx[0][0] = load8s(Wih0 + (      col) * Din + quad * 8, sRZ);
        wx[0][1] = load8s(Wih0 + ( 64 + col) * Din + quad * 8, sRZ);
        wx[0][2] = load8s(Wih0 + (128 + col) * Din + quad * 8, sN);
#pragma unroll
        for (int kb = 0; kb < 2; ++kb) {
            wh[kb][0] = load8s(Whh0 + (      col) * Hd + kb * 32 + quad * 8, sRZ);
            wh[kb][1] = load8s(Whh0 + ( 64 + col) * Hd + kb * 32 + quad * 8, sRZ);
            wh[kb][2] = load8s(Whh0 + (128 + col) * Hd + kb * 32 + quad * 8, sN);
        }
        brz0 = sRZ * (bih0[col] + bhh0[col]);
        brz1 = sRZ * (bih0[64 + col] + bhh0[64 + col]);
        bin_ = sN * bih0[128 + col];
        bhn_ = sN * bhh0[128 + col];
    } else {
#pragma unroll
        for (int kb = 0; kb < 2; ++kb) {
            wx[kb][0] = load8s(Wih1 + (      col) * Hd + kb * 32 + quad * 8, sRZ);
            wx[kb][1] = load8s(Wih1 + ( 64 + col) * Hd + kb * 32 + quad * 8, sRZ);
            wx[kb][2] = load8s(Wih1 + (128 + col) * Hd + kb * 32 + quad * 8, sN);
            wh[kb][0] = load8s(Whh1 + (      col) * Hd + kb * 32 + quad * 8, sRZ);
            wh[kb][1] = load8s(Whh1 + ( 64 + col) * Hd + kb * 32 + quad * 8, sRZ);
            wh[kb][2] = load8s(Whh1 + (128 + col) * Hd + kb * 32 + quad * 8, sN);
        }
        brz0 = sRZ * (bih1[col] + bhh1[col]);
        brz1 = sRZ * (bih1[64 + col] + bhh1[64 + col]);
        bin_ = sN * bih1[128 + col];
        bhn_ = sN * bhh1[128 + col];
    }

    const int rdoff = m * HS + quad * 8;          // lane part of A-read address (arena)
    const int xroff = m * XSTR + quad * 32;       // lane part of x-read address (bytes)
    const int wroff = (quad * 4) * HS + col;      // lane part of C-write address
    float hst[4] = {0.f, 0.f, 0.f, 0.f};
    __syncthreads();                               // drains staging DMAs too

    int ro = BUFE;                                // peel-0 reads zeros from buf1

    // ---------- peel i = 0 : L1 only; h1[-1]=0 so h-side MFMAs are skipped ----------
    if (grp == 0) {
        const char* xr = xstage + xroff;          // chunk0, step 0
        float4 a = *(const float4*)xr, b4 = *(const float4*)(xr + 16);
        half8 ax = cvt8(a, b4);
        f32x4 gr  = {brz0, brz0, brz0, brz0};
        f32x4 gz  = {brz1, brz1, brz1, brz1};
        f32x4 anx = {bin_, bin_, bin_, bin_};
        f32x4 anh = {bhn_, bhn_, bhn_, bhn_};
        gr  = MFMA(ax, wx[0][0], gr);
        gz  = MFMA(ax, wx[0][1], gz);
        anx = MFMA(ax, wx[0][2], anx);
        gate_update(gr, gz, anx, anh, hst, arena + ((ro ^ BUFE) + wroff), true);
    }
    __syncthreads();
    ro ^= BUFE;                                   // -> 0

    // ---------- main: i = 1..511, both groups active ----------
    for (int i = 1; i < Tlen; ++i) {
        const int wo = ro ^ BUFE;
        // once per 16 steps: stage chunk (i/16)+1 into the buffer not being read
        if ((i & (CHUNK - 1)) == 0 && i < Tlen - CHUNK)
            stage_chunk(x, xstage, wave, lane, b0, i + CHUNK, ((i >> 4) + 1) & 1);

        if (grp == 0) {
            const char* xr = xstage + ((i >> 4) & 1) * XBUFB + (i & 15) * 128 + xroff;
            float4 a = *(const float4*)xr, b4 = *(const float4*)(xr + 16);
            half8 ax = cvt8(a, b4);
            const _Float16* s1 = arena + (ro + rdoff);
            half8 ah0 = *(const half8*)s1;
            half8 ah1 = *(const half8*)(s1 + 32);
            f32x4 arx = {brz0, brz0, brz0, brz0};
            f32x4 azx = {brz1, brz1, brz1, brz1};
            f32x4 anx = {bin_, bin_, bin_, bin_};
            f32x4 arh = {0.f, 0.f, 0.f, 0.f};
            f32x4 azh = {0.f, 0.f, 0.f, 0.f};
            f32x4 anh = {bhn_, bhn_, bhn_, bhn_};
            // h-side first (critical path from ds_read); depth-2 chains
            arh = MFMA(ah0, wh[0][0], arh); arh = MFMA(ah1, wh[1][0], arh);
            azh = MFMA(ah0, wh[0][1], azh); azh = MFMA(ah1, wh[1][1], azh);
            anh = MFMA(ah0, wh[0][2], anh); anh = MFMA(ah1, wh[1][2], anh);
            arx = MFMA(ax, wx[0][0], arx);
            azx = MFMA(ax, wx[0][1], azx);
            anx = MFMA(ax, wx[0][2], anx);
            f32x4 gr = arx + arh, gz = azx + azh;
            gate_update(gr, gz, anx, anh, hst, arena + (wo + wroff), true);
        } else {
            const _Float16* s1 = arena + (ro + rdoff);            // h1[i-1]
            const _Float16* s2 = s1 + 2 * BUFE;                   // h2[i-2]
            half8 ax0 = *(const half8*)s1;
            half8 ax1 = *(const half8*)(s1 + 32);
            half8 ah0 = *(const half8*)s2;
            half8 ah1 = *(const half8*)(s2 + 32);
            f32x4 arx = {brz0, brz0, brz0, brz0};
            f32x4 azx = {brz1, brz1, brz1, brz1};
            f32x4 anx = {bin_, bin_, bin_, bin_};
            f32x4 arh = {0.f, 0.f, 0.f, 0.f};
            f32x4 azh = {0.f, 0.f, 0.f, 0.f};
            f32x4 anh = {bhn_, bhn_, bhn_, bhn_};
            arx = MFMA(ax0, wx[0][0], arx); arx = MFMA(ax1, wx[1][0], arx);
            azx = MFMA(ax0, wx[0][1], azx); azx = MFMA(ax1, wx[1][1], azx);
            anx = MFMA(ax0, wx[0][2], anx); anx = MFMA(ax1, wx[1][2], anx);
            arh = MFMA(ah0, wh[0][0], arh); arh = MFMA(ah1, wh[1][0], arh);
            azh = MFMA(ah0, wh[0][1], azh); azh = MFMA(ah1, wh[1][1], azh);
            anh = MFMA(ah0, wh[0][2], anh); anh = MFMA(ah1, wh[1][2], anh);
            f32x4 gr = arx + arh, gz = azx + azh;
            gate_update(gr, gz, anx, anh, hst, arena + (2 * BUFE + wo + wroff), true);
        }
        __syncthreads();
        ro = wo;
    }

    // ---------- peel i = T : L2 only, computes h2[T-1], no LDS writeback ----------
    if (grp == 1) {
        const _Float16* s1 = arena + (ro + rdoff);
        const _Float16* s2 = s1 + 2 * BUFE;
        half8 ax0 = *(const half8*)s1;
        half8 ax1 = *(const half8*)(s1 + 32);
        half8 ah0 = *(const half8*)s2;
        half8 ah1 = *(const half8*)(s2 + 32);
        f32x4 arx = {brz0, brz0, brz0, brz0};
        f32x4 azx = {brz1, brz1, brz1, brz1};
        f32x4 anx = {bin_, bin_, bin_, bin_};
        f32x4 arh = {0.f, 0.f, 0.f, 0.f};
        f32x4 azh = {0.f, 0.f, 0.f, 0.f};
        f32x4 anh = {bhn_, bhn_, bhn_, bhn_};
        arx = MFMA(ax0, wx[0][0], arx); arx = MFMA(ax1, wx[1][0], arx);
        azx = MFMA(ax0, wx[0][1], azx); azx = MFMA(ax1, wx[1][1], azx);
        anx = MFMA(ax0, wx[0][2], anx); anx = MFMA(ax1, wx[1][2], anx);
        arh = MFMA(ah0, wh[0][0], arh); arh = MFMA(ah1, wh[1][0], arh);
        azh = MFMA(ah0, wh[0][1], azh); azh = MFMA(ah1, wh[1][1], azh);
        anh = MFMA(ah0, wh[0][2], anh); anh = MFMA(ah1, wh[1][2], anh);
        f32x4 gr = arx + arh, gz = azx + azh;
        gate_update(gr, gz, anx, anh, hst, nullptr, false);
#pragma unroll
        for (int r = 0; r < 4; ++r) hfin[quad * 4 + r][col] = hst[r];
    }
    __syncthreads();
    if (tid < BT) {                                // FC head
        float acc = fcb[0];
        for (int c = 0; c < Hd; ++c) acc += hfin[tid][c] * fcw[c];
        out[b0 + tid] = acc;
    }
}

extern "C" void kernel_launch(void* const* d_in, const int* in_sizes, int n_in,
                              void* d_out, int out_size, void* d_ws, size_t ws_size,
                              hipStream_t stream) {
    gru_fused<<<dim3(Bsz / BT), dim3(512), 0, stream>>>(
        (const float*)d_in[0],
        (const float*)d_in[1], (const float*)d_in[2],
        (const float*)d_in[3], (const float*)d_in[4],
        (const float*)d_in[5], (const float*)d_in[6],
        (const float*)d_in[7], (const float*)d_in[8],
        (const float*)d_in[9], (const float*)d_in[10],
        (float*)d_out);
}

// Round 6
// 501.121 us; speedup vs baseline: 1.3214x; 1.1011x over previous
//
#include <hip/hip_runtime.h>

#define Bsz  2048
#define Tlen 512
#define Din  32
#define Hd   64
#define BT   16            // real batches per block (M=16 MFMA tile, no ghost rows)
#define HS   72            // h-tile row stride in f16 elems (144B, 16B-aligned reads)
#define BUFE 2048          // f16 elems per h buffer (4096 B) -> compile-time toggle
#define CHUNK 16           // x timesteps staged per global_load_lds burst
#define XSTR  2064         // LDS bytes per batch per chunk (2048 + 16 pad)
#define XBUFB (BT * XSTR)  // bytes per x chunk buffer (33024)

typedef _Float16 half8 __attribute__((ext_vector_type(8)));
typedef float    f32x4 __attribute__((ext_vector_type(4)));

// weights pre-scaled by -log2(e) (r,z) and -2*log2(e) (n). With E = 2^(scaled):
//   sigma(raw) = 1/(1+E),  tanh(raw_n) = (1-E_n)/(1+E_n)
// GRU update folds to ONE rcp:  h' = [E_z(1-E_n) + h(1+E_n)] / [(1+E_z)(1+E_n)]
#define MFMA(a, b, c) __builtin_amdgcn_mfma_f32_16x16x32_f16((a), (b), (c), 0, 0, 0)

__device__ __forceinline__ half8 load8s(const float* p, float s) {
    half8 r;
#pragma unroll
    for (int j = 0; j < 8; ++j) r[j] = (_Float16)(p[j] * s);
    return r;
}
__device__ __forceinline__ half8 cvt8(float4 a, float4 b) {
    half8 r;
    r[0] = (_Float16)a.x; r[1] = (_Float16)a.y; r[2] = (_Float16)a.z; r[3] = (_Float16)a.w;
    r[4] = (_Float16)b.x; r[5] = (_Float16)b.y; r[6] = (_Float16)b.z; r[7] = (_Float16)b.w;
    return r;
}

// gates + state update + (optional) LDS writeback; 5 transcendentals/row (was 6)
__device__ __forceinline__ void gate_update(const f32x4& gr, const f32x4& gz,
                                            const f32x4& anx, const f32x4& anh,
                                            float hst[4], _Float16* dst, bool wr) {
#pragma unroll
    for (int r = 0; r < 4; ++r) {
        float Er = __builtin_amdgcn_exp2f(gr[r]);
        float rr = __builtin_amdgcn_rcpf(1.0f + Er);
        float yy = anx[r] + rr * anh[r];
        float En = __builtin_amdgcn_exp2f(yy);
        float Ez = __builtin_amdgcn_exp2f(gz[r]);
        float num = Ez * (1.0f - En) + hst[r] * (1.0f + En);
        float den = (1.0f + Ez) * (1.0f + En);
        hst[r] = num * __builtin_amdgcn_rcpf(den);
        if (wr) dst[r * HS] = (_Float16)hst[r];
    }
}

// stage one 16-step x chunk (32 KB) into LDS buffer p via async global->LDS DMA
__device__ __forceinline__ void stage_chunk(const float* __restrict__ x, char* xs,
                                            int wave, int lane, int b0, int t0, int p) {
#pragma unroll
    for (int j = 0; j < 4; ++j) {
        const int g  = wave * 4 + j;
        const int b  = g >> 1;
        const int hh = g & 1;
        const float* gp = x + (size_t)(b0 + b) * (Tlen * Din) + (size_t)t0 * Din
                            + hh * 256 + lane * 4;
        char* lp = xs + p * XBUFB + b * XSTR + hh * 1024 + lane * 16;
        __builtin_amdgcn_global_load_lds(
            (const __attribute__((address_space(1))) void*)gp,
            (__attribute__((address_space(3))) void*)lp, 16, 0, 0);
    }
}

__global__ __launch_bounds__(512, 2)
void gru_fused(const float* __restrict__ x,
               const float* __restrict__ Wih0, const float* __restrict__ Whh0,
               const float* __restrict__ bih0, const float* __restrict__ bhh0,
               const float* __restrict__ Wih1, const float* __restrict__ Whh1,
               const float* __restrict__ bih1, const float* __restrict__ bhh1,
               const float* __restrict__ fcw,  const float* __restrict__ fcb,
               float* __restrict__ out)
{
    // arena: h1 buffers at [0],[BUFE]; h2 buffers at [2*BUFE],[3*BUFE]
    __shared__ _Float16 arena[4 * BUFE];
    __shared__ __attribute__((aligned(16))) char xstage[2 * XBUFB];
    __shared__ float hfin[BT][Hd];

    const int tid  = threadIdx.x;
    const int lane = tid & 63;
    const int wave = tid >> 6;
    const int grp  = wave >> 2;            // 0 = layer1 waves, 1 = layer2 waves
    const int wg   = wave & 3;             // which 16 gate-cols this wave owns
    const int m    = lane & 15;            // A-frag row = batch (ALL REAL)
    const int quad = lane >> 4;            // k-chunk (A/B), row-group (C/D)
    const int col  = (wg << 4) + m;        // gate/h column 0..63
    const int b0   = blockIdx.x << 4;      // 16 batches per block

    for (int idx = tid; idx < 4 * BUFE; idx += 512) arena[idx] = (_Float16)0.f;

    // pre-stage chunks 0 (steps 0..15 -> buf0) and 1 (steps 16..31 -> buf1)
    stage_chunk(x, xstage, wave, lane, b0, 0, 0);
    stage_chunk(x, xstage, wave, lane, b0, CHUNK, 1);

    const float sRZ = -1.44269504f;        // -log2(e)
    const float sN  = -2.88539008f;        // -2*log2(e)

    // ---- persistent pre-scaled weight B-fragments (B[k][n] = W[n][k]) ----
    half8 wx[2][3], wh[2][3];
    float brz0, brz1, bin_, bhn_;

    if (grp == 0) {
        wx[0][0] = load8s(Wih0 + (      col) * Din + quad * 8, sRZ);
        wx[0][1] = load8s(Wih0 + ( 64 + col) * Din + quad * 8, sRZ);
        wx[0][2] = load8s(Wih0 + (128 + col) * Din + quad * 8, sN);
#pragma unroll
        for (int kb = 0; kb < 2; ++kb) {
            wh[kb][0] = load8s(Whh0 + (      col) * Hd + kb * 32 + quad * 8, sRZ);
            wh[kb][1] = load8s(Whh0 + ( 64 + col) * Hd + kb * 32 + quad * 8, sRZ);
            wh[kb][2] = load8s(Whh0 + (128 + col) * Hd + kb * 32 + quad * 8, sN);
        }
        brz0 = sRZ * (bih0[col] + bhh0[col]);
        brz1 = sRZ * (bih0[64 + col] + bhh0[64 + col]);
        bin_ = sN * bih0[128 + col];
        bhn_ = sN * bhh0[128 + col];
    } else {
#pragma unroll
        for (int kb = 0; kb < 2; ++kb) {
            wx[kb][0] = load8s(Wih1 + (      col) * Hd + kb * 32 + quad * 8, sRZ);
            wx[kb][1] = load8s(Wih1 + ( 64 + col) * Hd + kb * 32 + quad * 8, sRZ);
            wx[kb][2] = load8s(Wih1 + (128 + col) * Hd + kb * 32 + quad * 8, sN);
            wh[kb][0] = load8s(Whh1 + (      col) * Hd + kb * 32 + quad * 8, sRZ);
            wh[kb][1] = load8s(Whh1 + ( 64 + col) * Hd + kb * 32 + quad * 8, sRZ);
            wh[kb][2] = load8s(Whh1 + (128 + col) * Hd + kb * 32 + quad * 8, sN);
        }
        brz0 = sRZ * (bih1[col] + bhh1[col]);
        brz1 = sRZ * (bih1[64 + col] + bhh1[64 + col]);
        bin_ = sN * bih1[128 + col];
        bhn_ = sN * bhh1[128 + col];
    }

    const int rdoff = m * HS + quad * 8;          // lane part of A-read address (arena)
    const int xroff = m * XSTR + quad * 32;       // lane part of x-read address (bytes)
    const int wroff = (quad * 4) * HS + col;      // lane part of C-write address
    float hst[4] = {0.f, 0.f, 0.f, 0.f};
    float4 xa, xb;
    __syncthreads();                               // drains staging DMAs too

    // invariant: entering a step body for step j, xa/xb hold x[j] (grp0 only)
    if (grp == 0) {
        const char* xr = xstage + xroff;           // x[0]
        xa = *(const float4*)xr; xb = *(const float4*)(xr + 16);
    }

// one recurrence step; RO/WO are compile-time buffer offsets. Ends pre-barrier
// with the x preload for step I+1 (x chunk buffers are stable across barriers).
#define STEP(I, RO, WO)                                                          \
  do {                                                                           \
    if (grp == 0) {                                                              \
      half8 ax = cvt8(xa, xb);                                                   \
      const _Float16* s1 = arena + (RO) + rdoff;                                 \
      half8 ah0 = *(const half8*)s1;                                             \
      half8 ah1 = *(const half8*)(s1 + 32);                                      \
      f32x4 arx = {brz0, brz0, brz0, brz0};                                      \
      f32x4 azx = {brz1, brz1, brz1, brz1};                                      \
      f32x4 anx = {bin_, bin_, bin_, bin_};                                      \
      f32x4 arh = {0.f,0.f,0.f,0.f}, azh = {0.f,0.f,0.f,0.f};                    \
      f32x4 anh = {bhn_, bhn_, bhn_, bhn_};                                      \
      arh = MFMA(ah0, wh[0][0], arh); arh = MFMA(ah1, wh[1][0], arh);            \
      azh = MFMA(ah0, wh[0][1], azh); azh = MFMA(ah1, wh[1][1], azh);            \
      anh = MFMA(ah0, wh[0][2], anh); anh = MFMA(ah1, wh[1][2], anh);            \
      arx = MFMA(ax, wx[0][0], arx);                                             \
      azx = MFMA(ax, wx[0][1], azx);                                             \
      anx = MFMA(ax, wx[0][2], anx);                                             \
      f32x4 gr = arx + arh, gz = azx + azh;                                      \
      gate_update(gr, gz, anx, anh, hst, arena + (WO) + wroff, true);            \
      { const int nx = ((I) + 1 < Tlen) ? (I) + 1 : (I);                         \
        const char* xr = xstage + ((nx >> 4) & 1) * XBUFB + (nx & 15) * 128      \
                         + xroff;                                                \
        xa = *(const float4*)xr; xb = *(const float4*)(xr + 16); }               \
    } else {                                                                     \
      const _Float16* s1 = arena + (RO) + rdoff;              /* h1[I-1] */      \
      const _Float16* s2 = s1 + 2 * BUFE;                     /* h2[I-2] */      \
      half8 ax0 = *(const half8*)s1;                                             \
      half8 ax1 = *(const half8*)(s1 + 32);                                      \
      half8 ah0 = *(const half8*)s2;                                             \
      half8 ah1 = *(const half8*)(s2 + 32);                                      \
      f32x4 arx = {brz0, brz0, brz0, brz0};                                      \
      f32x4 azx = {brz1, brz1, brz1, brz1};                                      \
      f32x4 anx = {bin_, bin_, bin_, bin_};                                      \
      f32x4 arh = {0.f,0.f,0.f,0.f}, azh = {0.f,0.f,0.f,0.f};                    \
      f32x4 anh = {bhn_, bhn_, bhn_, bhn_};                                      \
      arx = MFMA(ax0, wx[0][0], arx); arx = MFMA(ax1, wx[1][0], arx);            \
      azx = MFMA(ax0, wx[0][1], azx); azx = MFMA(ax1, wx[1][1], azx);            \
      anx = MFMA(ax0, wx[0][2], anx); anx = MFMA(ax1, wx[1][2], anx);            \
      arh = MFMA(ah0, wh[0][0], arh); arh = MFMA(ah1, wh[1][0], arh);            \
      azh = MFMA(ah0, wh[0][1], azh); azh = MFMA(ah1, wh[1][1], azh);            \
      anh = MFMA(ah0, wh[0][2], anh); anh = MFMA(ah1, wh[1][2], anh);            \
      f32x4 gr = arx + arh, gz = azx + azh;                                      \
      gate_update(gr, gz, anx, anh, hst, arena + (2 * BUFE) + (WO) + wroff,      \
                  true);                                                         \
    }                                                                            \
    __syncthreads();                                                             \
  } while (0)

    // ---------- peel i = 0 : L1 only; h1[-1]=0 so h-side MFMAs are skipped ----------
    if (grp == 0) {
        half8 ax = cvt8(xa, xb);
        f32x4 gr  = {brz0, brz0, brz0, brz0};
        f32x4 gz  = {brz1, brz1, brz1, brz1};
        f32x4 anx = {bin_, bin_, bin_, bin_};
        f32x4 anh = {bhn_, bhn_, bhn_, bhn_};
        gr  = MFMA(ax, wx[0][0], gr);
        gz  = MFMA(ax, wx[0][1], gz);
        anx = MFMA(ax, wx[0][2], anx);
        gate_update(gr, gz, anx, anh, hst, arena + 0 + wroff, true);
        const char* xr = xstage + 128 + xroff;     // x[1] (chunk 0, slot 1)
        xa = *(const float4*)xr; xb = *(const float4*)(xr + 16);
    }
    __syncthreads();

    // ---------- main: steps 1..511; odd steps read buf0/write buf1, even reverse ----
    for (int i = 1; i + 1 < Tlen; i += 2) {
        STEP(i, 0, BUFE);                          // odd step
        if (((i + 1) & (CHUNK - 1)) == 0 && (i + 1) < Tlen - CHUNK)
            stage_chunk(x, xstage, wave, lane, b0, i + 1 + CHUNK,
                        (((i + 1) >> 4) + 1) & 1);
        STEP(i + 1, BUFE, 0);                      // even step
    }
    STEP(Tlen - 1, 0, BUFE);                       // step 511

    // ---------- peel i = T : L2 only, computes h2[T-1], no LDS writeback ----------
    if (grp == 1) {
        const _Float16* s1 = arena + BUFE + rdoff;            // h1[511]
        const _Float16* s2 = s1 + 2 * BUFE;                   // h2[510]
        half8 ax0 = *(const half8*)s1;
        half8 ax1 = *(const half8*)(s1 + 32);
        half8 ah0 = *(const half8*)s2;
        half8 ah1 = *(const half8*)(s2 + 32);
        f32x4 arx = {brz0, brz0, brz0, brz0};
        f32x4 azx = {brz1, brz1, brz1, brz1};
        f32x4 anx = {bin_, bin_, bin_, bin_};
        f32x4 arh = {0.f,0.f,0.f,0.f}, azh = {0.f,0.f,0.f,0.f};
        f32x4 anh = {bhn_, bhn_, bhn_, bhn_};
        arx = MFMA(ax0, wx[0][0], arx); arx = MFMA(ax1, wx[1][0], arx);
        azx = MFMA(ax0, wx[0][1], azx); azx = MFMA(ax1, wx[1][1], azx);
        anx = MFMA(ax0, wx[0][2], anx); anx = MFMA(ax1, wx[1][2], anx);
        arh = MFMA(ah0, wh[0][0], arh); arh = MFMA(ah1, wh[1][0], arh);
        azh = MFMA(ah0, wh[0][1], azh); azh = MFMA(ah1, wh[1][1], azh);
        anh = MFMA(ah0, wh[0][2], anh); anh = MFMA(ah1, wh[1][2], anh);
        f32x4 gr = arx + arh, gz = azx + azh;
        gate_update(gr, gz, anx, anh, hst, nullptr, false);
#pragma unroll
        for (int r = 0; r < 4; ++r) hfin[quad * 4 + r][col] = hst[r];
    }
    __syncthreads();
    if (tid < BT) {                                // FC head
        float acc = fcb[0];
        for (int c = 0; c < Hd; ++c) acc += hfin[tid][c] * fcw[c];
        out[b0 + tid] = acc;
    }
#undef STEP
}

extern "C" void kernel_launch(void* const* d_in, const int* in_sizes, int n_in,
                              void* d_out, int out_size, void* d_ws, size_t ws_size,
                              hipStream_t stream) {
    gru_fused<<<dim3(Bsz / BT), dim3(512), 0, stream>>>(
        (const float*)d_in[0],
        (const float*)d_in[1], (const float*)d_in[2],
        (const float*)d_in[3], (const float*)d_in[4],
        (const float*)d_in[5], (const float*)d_in[6],
        (const float*)d_in[7], (const float*)d_in[8],
        (const float*)d_in[9], (const float*)d_in[10],
        (float*)d_out);
}